// Round 2
// baseline (538.870 us; speedup 1.0000x reference)
//
#include <hip/hip_runtime.h>

// MiniSelfAttention: B=8, T=2048, D=1024, fp32 in/out, fp16 MFMA internally.
// R9: 8-phase 256x256 GEMM (port of the m201/HipKittens schedule to this op).
//  - tile 256x256, BK=64, 8 waves (2Mx4N), per-wave 128x64 output (acc[8][4]).
//  - LDS 128KB: 2 K-tile double buffer; each K-tile = A(256x64) + B(256x64)
//    fp16, stored as half-tiles of 128 rows x 128B.
//  - per K-tile: 4 phases, each {ds_read subtile, [stage], barrier,
//    lgkmcnt(0), setprio(1), 16 MFMA, setprio(0), barrier}. Phase 0 reads all
//    8 B-frags + A-frags m0,m1 (12 ds_read_b128) and issues the FULL staging
//    of K-tile t+1 (8 GLD16/wave -> ~4 phases of DMA flight); phase 3 drains
//    vmcnt before the K-tile-closing barrier.
//  - LDS chunk swizzle c' = c ^ (row&7) on 16B chunks of the 128B row:
//    full-wave ds_read_b128 hits each bank-quad exactly 8x (conflict-free).
//    global_load_lds writes linearly, so the swizzle is applied by permuting
//    the per-lane GLOBAL source chunk (both-sides-or-neither rule).
//  - bijective XCD remap (m204) on the flattened block id for L2 locality.
//
// ws layout (MB):
//   [0,6)    WqkvT = WqT|WkT|WvT contiguous (fp16 [3072][1024])
//   [6,8)    WpT fp16
//   [8,40)   q fp16 [8][2048][1024]   (later overwritten by ctx)
//   [40,72)  k fp16
//   [72,104) vT fp16 [8][1024][2048]
//   [104,136) x16 fp16 (dead after QKV), overlaid by:
//   [104,168) S fp16 [8][2048][2048]  (softmaxed in place -> P)

typedef _Float16 half_t;
typedef _Float16 half8 __attribute__((ext_vector_type(8)));
typedef float floatx4 __attribute__((ext_vector_type(4)));

// async global->LDS, 16B per lane; LDS dest = wave-uniform base + lane*16
#define GLD16(gp, lp)                                                          \
    __builtin_amdgcn_global_load_lds(                                          \
        (const __attribute__((address_space(1))) void*)(gp),                   \
        (__attribute__((address_space(3))) void*)(lp), 16, 0, 0)

#define WAIT_VM0()   asm volatile("s_waitcnt vmcnt(0)" ::: "memory")
#define WAIT_LGKM0() asm volatile("s_waitcnt lgkmcnt(0)" ::: "memory")
#define WAIT_LGKM8() asm volatile("s_waitcnt lgkmcnt(8)" ::: "memory")
#define BARRIER()   do { asm volatile("" ::: "memory");                        \
                         __builtin_amdgcn_s_barrier();                         \
                         asm volatile("" ::: "memory"); } while (0)

// ---------------------------------------------------------------------------
// fp16 NT GEMM, 8-phase schedule. EPI: 0 = fp16 C; 1 = fp32 C + bias;
// 2 = QKV-routed (q*1/32, k, vT). Requires M,N multiples of 256, K of 64.
// ---------------------------------------------------------------------------
template<int EPI>
__global__ __launch_bounds__(512, 2)
void gemm16(const half_t* __restrict__ A, const half_t* __restrict__ B,
            void* __restrict__ Cv, void* __restrict__ C2, void* __restrict__ C3,
            const float* __restrict__ bias, int K, int lda, int ldb, int ldc,
            long long bsA, long long bsB, long long bsC)
{
    // [buf][half][128 rows][64 halves] each; 64KB + 64KB = 128KB total
    __shared__ half_t As[2 * 2 * 128 * 64];
    __shared__ half_t Bs[2 * 2 * 128 * 64];

    const int tid  = threadIdx.x;
    const int lane = tid & 63;
    const int w    = tid >> 6;           // 0..7
    const int wm   = w >> 2;             // 0..1 : wave row (128 C-rows)
    const int wn   = w & 3;              // 0..3 : wave col (64 C-cols)

    // bijective XCD remap (m204) of flattened block id
    int bx = blockIdx.x, by = blockIdx.y, bz = blockIdx.z;
    {
        const int gx = gridDim.x, gy = gridDim.y;
        const int nwg = gx * gy * (int)gridDim.z;
        int lid = (bz * gy + by) * gx + bx;
        const int qq = nwg >> 3, rr = nwg & 7;
        const int xcd = lid & 7, off = lid >> 3;
        lid = (xcd < rr ? xcd * (qq + 1) : rr * (qq + 1) + (xcd - rr) * qq) + off;
        bx = lid % gx; lid /= gx;
        by = lid % gy; bz = lid / gy;
    }
    const long long z = bz;
    const int rowBase = by * 256;
    const int colBase = bx * 256;

    // ---- staging setup: wave w stages rows [w*16, w*16+16) of each of the
    // 4 half-tiles {A0,A1,B0,B1}; 2 GLD16 per half-tile (8 rows each).
    // Lane l covers LDS (row srow=l>>3, chunk slot l&7); that slot must hold
    // global 16B-chunk (l&7)^srow (write-side inverse of the read swizzle).
    const int srow = lane >> 3;                 // 0..7
    const int schk = (lane & 7) ^ srow;         // swizzled source chunk
    const half_t* gp[4];
    int jstep[4];
    half_t* lp[4];
    #pragma unroll
    for (int i = 0; i < 4; ++i) {
        const bool ia = (i < 2);
        const int ld  = ia ? lda : ldb;
        const int rb  = (ia ? rowBase : colBase) + (i & 1) * 128 + w * 16 + srow;
        gp[i] = (ia ? A + z * bsA : B + z * bsB) + (long long)rb * ld + schk * 8;
        jstep[i] = 8 * ld;
        lp[i] = (ia ? As : Bs) + (i & 1) * 8192 + w * 1024;   // w*16 rows * 64
    }

    // ---- fragment read setup (read-side swizzle: chunk ^= row&7)
    const int fr  = lane & 15;
    const int q   = lane >> 4;                  // 0..3 : 16B chunk in k-step
    const int rsw = fr & 7;
    const half_t* Abase = As + wm * 8192 + fr * 64;
    const half_t* Bbase = Bs + (wn >> 1) * 8192 + ((wn & 1) * 64 + fr) * 64;
    const int ko0 = ((0 + q) ^ rsw) * 8;        // ks=0 chunk offset (halves)
    const int ko1 = ((4 + q) ^ rsw) * 8;        // ks=1

    floatx4 acc[8][4];
    #pragma unroll
    for (int m = 0; m < 8; ++m)
        #pragma unroll
        for (int n = 0; n < 4; ++n)
            #pragma unroll
            for (int j = 0; j < 4; ++j) acc[m][n][j] = 0.0f;

    const int nIter = K >> 6;

    // ---- prologue: stage K-tile 0 into buffer 0
    #pragma unroll
    for (int i = 0; i < 4; ++i) {
        GLD16(gp[i],            lp[i]);
        GLD16(gp[i] + jstep[i], lp[i] + 512);
    }
    WAIT_VM0();
    BARRIER();

    for (int t = 0; t < nIter; ++t) {
        const int cbuf = (t & 1) << 14;         // current buffer (halves)
        const int nbuf = 16384 - cbuf;          // next buffer
        half8 bf[4][2], af[2][2];

        // ================= phase 0 =================
        // stage ALL of K-tile t+1 (8 GLD16): ~4 phases of flight before drain
        if (t + 1 < nIter) {
            const int kk = (t + 1) << 6;
            #pragma unroll
            for (int i = 0; i < 4; ++i) {
                GLD16(gp[i] + kk,            lp[i] + nbuf);
                GLD16(gp[i] + kk + jstep[i], lp[i] + nbuf + 512);
            }
        }
        // 12 ds_read_b128: all B-frags + A-frags m0,m1
        #pragma unroll
        for (int n = 0; n < 4; ++n) {
            bf[n][0] = *(const half8*)(Bbase + cbuf + n * 1024 + ko0);
            bf[n][1] = *(const half8*)(Bbase + cbuf + n * 1024 + ko1);
        }
        af[0][0] = *(const half8*)(Abase + cbuf + 0 * 1024 + ko0);
        af[0][1] = *(const half8*)(Abase + cbuf + 0 * 1024 + ko1);
        af[1][0] = *(const half8*)(Abase + cbuf + 1 * 1024 + ko0);
        af[1][1] = *(const half8*)(Abase + cbuf + 1 * 1024 + ko1);
        WAIT_LGKM8();
        BARRIER();
        WAIT_LGKM0();
        __builtin_amdgcn_s_setprio(1);
        #pragma unroll
        for (int ml = 0; ml < 2; ++ml)
            #pragma unroll
            for (int n = 0; n < 4; ++n)
                #pragma unroll
                for (int ks = 0; ks < 2; ++ks)
                    acc[ml][n] = __builtin_amdgcn_mfma_f32_16x16x32_f16(
                        af[ml][ks], bf[n][ks], acc[ml][n], 0, 0, 0);
        __builtin_amdgcn_s_setprio(0);
        BARRIER();

        // ================= phases 1..3 =================
        #pragma unroll
        for (int p = 1; p < 4; ++p) {
            #pragma unroll
            for (int ml = 0; ml < 2; ++ml) {
                af[ml][0] = *(const half8*)(Abase + cbuf + (p * 2 + ml) * 1024 + ko0);
                af[ml][1] = *(const half8*)(Abase + cbuf + (p * 2 + ml) * 1024 + ko1);
            }
            BARRIER();
            WAIT_LGKM0();
            __builtin_amdgcn_s_setprio(1);
            #pragma unroll
            for (int ml = 0; ml < 2; ++ml)
                #pragma unroll
                for (int n = 0; n < 4; ++n)
                    #pragma unroll
                    for (int ks = 0; ks < 2; ++ks)
                        acc[p * 2 + ml][n] = __builtin_amdgcn_mfma_f32_16x16x32_f16(
                            af[ml][ks], bf[n][ks], acc[p * 2 + ml][n], 0, 0, 0);
            __builtin_amdgcn_s_setprio(0);
            if (p == 3) WAIT_VM0();   // K-tile t+1's 8 loads landed (4-phase flight)
            BARRIER();
        }
    }

    // ---- epilogue: C/D layout col=lane&15, row=(lane>>4)*4+reg (verified)
    const int ecol = lane & 15;
    const int q4   = (lane >> 4) * 4;
    #pragma unroll
    for (int m = 0; m < 8; ++m) {
        #pragma unroll
        for (int n = 0; n < 4; ++n) {
            const int gcol = colBase + wn * 64 + n * 16 + ecol;
            #pragma unroll
            for (int r = 0; r < 4; ++r) {
                const int grow = rowBase + wm * 128 + m * 16 + q4 + r;
                float v = acc[m][n][r];
                if (EPI == 0) {
                    ((half_t*)Cv)[z * bsC + (long long)grow * ldc + gcol] = (half_t)v;
                } else if (EPI == 1) {
                    ((float*)Cv)[(long long)grow * ldc + gcol] = v + bias[gcol];
                } else {
                    // QKV routing: 256-col tile lies inside one of q/k/v's
                    // 1024-col spans (boundaries are multiples of 256)
                    const int mat = colBase >> 10;      // 0=q, 1=k, 2=v
                    const int c   = gcol & 1023;
                    if (mat == 0) {
                        ((half_t*)Cv)[(long long)grow * 1024 + c] = (half_t)(v * 0.03125f);
                    } else if (mat == 1) {
                        ((half_t*)C2)[(long long)grow * 1024 + c] = (half_t)v;
                    } else {
                        // vT[b][c][t], b=grow>>11, t=grow&2047
                        const long long bb = grow >> 11;
                        const long long tt = grow & 2047;
                        ((half_t*)C3)[bb * (1024LL * 2048) + (long long)c * 2048 + tt] = (half_t)v;
                    }
                }
            }
        }
    }
}

// fp32 -> fp16 flat cast, 8 elems/thread
__global__ __launch_bounds__(256)
void cast16(const float* __restrict__ x, half_t* __restrict__ y)
{
    const long long i = ((long long)blockIdx.x * 256 + threadIdx.x) * 8;
    floatx4 a = *(const floatx4*)(x + i);
    floatx4 b = *(const floatx4*)(x + i + 4);
    half8 h;
    #pragma unroll
    for (int j = 0; j < 4; ++j) { h[j] = (half_t)a[j]; h[j + 4] = (half_t)b[j]; }
    *(half8*)(y + i) = h;
}

// 1024x1024 fp32 -> fp16 transposed; grid.z selects which weight
__global__ __launch_bounds__(256)
void cast_transpose4(const float* __restrict__ W0, const float* __restrict__ W1,
                     const float* __restrict__ W2, const float* __restrict__ W3,
                     half_t* __restrict__ WT)
{
    const float* W = (blockIdx.z == 0) ? W0 : (blockIdx.z == 1) ? W1
                   : (blockIdx.z == 2) ? W2 : W3;
    half_t* O = WT + (long long)blockIdx.z * 1024 * 1024;
    __shared__ float t[32][33];
    const int bx = blockIdx.x * 32, by = blockIdx.y * 32;
    const int tx = threadIdx.x, ty = threadIdx.y;
    #pragma unroll
    for (int i = 0; i < 32; i += 8)
        t[ty + i][tx] = W[(long long)(by + ty + i) * 1024 + bx + tx];
    __syncthreads();
    #pragma unroll
    for (int i = 0; i < 32; i += 8)
        O[(long long)(bx + ty + i) * 1024 + by + tx] = (half_t)t[tx][ty + i];
}

// in-place fp16 row softmax over 2048; one 256-thr block per row; half8 I/O
__global__ __launch_bounds__(256)
void softmax_rows(half_t* __restrict__ S)
{
    const long long base = (long long)blockIdx.x * 2048;
    const int t = threadIdx.x;
    half8 h = *(const half8*)(S + base + t * 8);
    float v[8];
    #pragma unroll
    for (int i = 0; i < 8; ++i) v[i] = (float)h[i];
    float m = -3.0e38f;
    #pragma unroll
    for (int i = 0; i < 8; ++i) m = fmaxf(m, v[i]);
    #pragma unroll
    for (int off = 32; off > 0; off >>= 1) m = fmaxf(m, __shfl_down(m, off));
    __shared__ float redm[4], reds[4];
    const int lane = t & 63, wid = t >> 6;
    if (lane == 0) redm[wid] = m;
    __syncthreads();
    const float M = fmaxf(fmaxf(redm[0], redm[1]), fmaxf(redm[2], redm[3]));
    float s = 0.f;
    #pragma unroll
    for (int i = 0; i < 8; ++i) { v[i] = __expf(v[i] - M); s += v[i]; }
    #pragma unroll
    for (int off = 32; off > 0; off >>= 1) s += __shfl_down(s, off);
    if (lane == 0) reds[wid] = s;
    __syncthreads();
    const float inv = 1.0f / (reds[0] + reds[1] + reds[2] + reds[3]);
    #pragma unroll
    for (int i = 0; i < 8; ++i) h[i] = (half_t)(v[i] * inv);
    *(half8*)(S + base + t * 8) = h;
}

extern "C" void kernel_launch(void* const* d_in, const int* in_sizes, int n_in,
                              void* d_out, int out_size, void* d_ws, size_t ws_size,
                              hipStream_t stream)
{
    const float* x  = (const float*)d_in[0];
    const float* Wq = (const float*)d_in[1];
    const float* Wk = (const float*)d_in[2];
    const float* Wv = (const float*)d_in[3];
    const float* Wp = (const float*)d_in[4];
    const float* bp = (const float*)d_in[5];
    float* out = (float*)d_out;

    char* ws = (char*)d_ws;
    const long long MB = 1024LL * 1024LL;
    half_t* WqkvT = (half_t*)(ws + 0 * MB);   // [3072][1024] = WqT|WkT|WvT
    half_t* WpT   = (half_t*)(ws + 6 * MB);
    half_t* q     = (half_t*)(ws + 8 * MB);   // [8][2048][1024]; later ctx
    half_t* k     = (half_t*)(ws + 40 * MB);
    half_t* vT    = (half_t*)(ws + 72 * MB);  // [8][1024][2048]
    half_t* x16   = (half_t*)(ws + 104 * MB); // dead after QKV
    half_t* S     = (half_t*)(ws + 104 * MB); // [8][2048][2048] fp16, overlays x16

    dim3 blk(512);
    cast16<<<8192, dim3(256), 0, stream>>>(x, x16);
    cast_transpose4<<<dim3(32, 32, 4), dim3(32, 8), 0, stream>>>(Wq, Wk, Wv, Wp, WqkvT);

    // fused QKV: [16384,1024] @ [3072,1024]^T, routed epilogue. 768 blocks.
    gemm16<2><<<dim3(12, 64, 1), blk, 0, stream>>>(
        x16, WqkvT, q, k, vT, nullptr, 1024, 1024, 1024, 0, 0, 0, 0);

    // S = q @ k^T (fp16 out), all 8 batches. 512 blocks.
    gemm16<0><<<dim3(8, 8, 8), blk, 0, stream>>>(
        q, k, S, nullptr, nullptr, nullptr, 1024, 1024, 1024, 2048,
        2048LL * 1024, 2048LL * 1024, 2048LL * 2048);

    // P = softmax(S) in place
    softmax_rows<<<8 * 2048, dim3(256), 0, stream>>>(S);

    // ctx = P @ vT^T (fp16), overwrites q. 256 blocks.
    gemm16<0><<<dim3(4, 8, 8), blk, 0, stream>>>(
        S, vT, q, nullptr, nullptr, nullptr, 2048, 2048, 2048, 1024,
        2048LL * 2048, 1024LL * 2048, 2048LL * 1024);

    // out = ctx @ WpT^T + bp (fp32). 256 blocks.
    gemm16<1><<<dim3(4, 64, 1), blk, 0, stream>>>(
        q, WpT, out, nullptr, nullptr, bp, 1024, 1024, 1024, 1024, 0, 0, 0);
}

// Round 3
// 490.431 us; speedup vs baseline: 1.0988x; 1.0988x over previous
//
#include <hip/hip_runtime.h>

// MiniSelfAttention: B=8, T=2048, D=1024, fp32 in/out, fp16 MFMA internally.
// R10: 256x256/BK=64 GEMM with ONE barrier per K-tile + in-register pipeline.
//  - R9's lockstep 8-barriers-per-K-tile serialized the DS unit against the
//    MFMA pipe (MfmaUtil 21%). The only real hazard is the LDS buffer swap,
//    so: per K-tile {phase0: read bf(8)+af0(4), issue full DMA of tile t+1;
//    then 4 MFMA slices with ping-pong afA/afB register prefetch one slice
//    ahead; vmcnt(0); s_barrier}. Compiler emits counted lgkmcnt between
//    ds_read and dependent MFMA, so DS traffic overlaps the MFMA bursts.
//  - DMA flight = ~1 full K-tile (~2500cy) before the vmcnt(0) -> drain free.
//  - Geometry/swizzle/epilogues identical to R9 (verified correct):
//    8 waves 2Mx4N, per-wave 128x64 (acc[8][4]), LDS 128KB 2-buffer,
//    chunk swizzle c' = c ^ (row&7) (write side via permuted global source),
//    bijective XCD remap.
//
// ws layout (MB):
//   [0,6)    WqkvT = WqT|WkT|WvT contiguous (fp16 [3072][1024])
//   [6,8)    WpT fp16
//   [8,40)   q fp16 [8][2048][1024]   (later overwritten by ctx)
//   [40,72)  k fp16
//   [72,104) vT fp16 [8][1024][2048]
//   [104,136) x16 fp16 (dead after QKV), overlaid by:
//   [104,168) S fp16 [8][2048][2048]  (softmaxed in place -> P)

typedef _Float16 half_t;
typedef _Float16 half8 __attribute__((ext_vector_type(8)));
typedef float floatx4 __attribute__((ext_vector_type(4)));

// async global->LDS, 16B per lane; LDS dest = wave-uniform base + lane*16
#define GLD16(gp, lp)                                                          \
    __builtin_amdgcn_global_load_lds(                                          \
        (const __attribute__((address_space(1))) void*)(gp),                   \
        (__attribute__((address_space(3))) void*)(lp), 16, 0, 0)

#define WAIT_VM0()  asm volatile("s_waitcnt vmcnt(0)" ::: "memory")
#define BARRIER()   do { asm volatile("" ::: "memory");                        \
                         __builtin_amdgcn_s_barrier();                         \
                         asm volatile("" ::: "memory"); } while (0)

// ---------------------------------------------------------------------------
// fp16 NT GEMM. EPI: 0 = fp16 C; 1 = fp32 C + bias; 2 = QKV-routed.
// Requires M,N multiples of 256, K of 64 (all launches satisfy this).
// ---------------------------------------------------------------------------
template<int EPI>
__global__ __launch_bounds__(512, 2)
void gemm16(const half_t* __restrict__ A, const half_t* __restrict__ B,
            void* __restrict__ Cv, void* __restrict__ C2, void* __restrict__ C3,
            const float* __restrict__ bias, int K, int lda, int ldb, int ldc,
            long long bsA, long long bsB, long long bsC)
{
    // [buf][half][128 rows][64 halves] each; 64KB + 64KB = 128KB total
    __shared__ half_t As[2 * 2 * 128 * 64];
    __shared__ half_t Bs[2 * 2 * 128 * 64];

    const int tid  = threadIdx.x;
    const int lane = tid & 63;
    const int w    = tid >> 6;           // 0..7
    const int wm   = w >> 2;             // 0..1 : wave row (128 C-rows)
    const int wn   = w & 3;              // 0..3 : wave col (64 C-cols)

    // bijective XCD remap (m204) of flattened block id
    int bx = blockIdx.x, by = blockIdx.y, bz = blockIdx.z;
    {
        const int gx = gridDim.x, gy = gridDim.y;
        const int nwg = gx * gy * (int)gridDim.z;
        int lid = (bz * gy + by) * gx + bx;
        const int qq = nwg >> 3, rr = nwg & 7;
        const int xcd = lid & 7, off = lid >> 3;
        lid = (xcd < rr ? xcd * (qq + 1) : rr * (qq + 1) + (xcd - rr) * qq) + off;
        bx = lid % gx; lid /= gx;
        by = lid % gy; bz = lid / gy;
    }
    const long long z = bz;
    const int rowBase = by * 256;
    const int colBase = bx * 256;

    // ---- staging setup: wave w stages rows [w*16, w*16+16) of each of the
    // 4 half-tiles {A0,A1,B0,B1}; 2 GLD16 per half-tile (8 rows each).
    // Lane l covers LDS (row srow=l>>3, chunk slot l&7); that slot must hold
    // global 16B-chunk (l&7)^srow (write-side inverse of the read swizzle).
    const int srow = lane >> 3;                 // 0..7
    const int schk = (lane & 7) ^ srow;         // swizzled source chunk
    const half_t* gp[4];
    int jstep[4];
    half_t* lp[4];
    #pragma unroll
    for (int i = 0; i < 4; ++i) {
        const bool ia = (i < 2);
        const int ld  = ia ? lda : ldb;
        const int rb  = (ia ? rowBase : colBase) + (i & 1) * 128 + w * 16 + srow;
        gp[i] = (ia ? A + z * bsA : B + z * bsB) + (long long)rb * ld + schk * 8;
        jstep[i] = 8 * ld;
        lp[i] = (ia ? As : Bs) + (i & 1) * 8192 + w * 1024;   // w*16 rows * 64
    }

    // ---- fragment read setup (read-side swizzle: chunk ^= row&7)
    const int fr  = lane & 15;
    const int q   = lane >> 4;                  // 0..3 : 16B chunk in k-step
    const int rsw = fr & 7;
    const half_t* Abase = As + wm * 8192 + fr * 64;
    const half_t* Bbase = Bs + (wn >> 1) * 8192 + ((wn & 1) * 64 + fr) * 64;
    const int ko0 = ((0 + q) ^ rsw) * 8;        // ks=0 chunk offset (halves)
    const int ko1 = ((4 + q) ^ rsw) * 8;        // ks=1

    floatx4 acc[8][4];
    #pragma unroll
    for (int m = 0; m < 8; ++m)
        #pragma unroll
        for (int n = 0; n < 4; ++n)
            #pragma unroll
            for (int j = 0; j < 4; ++j) acc[m][n][j] = 0.0f;

    const int nIter = K >> 6;

    // ---- prologue: stage K-tile 0 into buffer 0, drain, publish
    #pragma unroll
    for (int i = 0; i < 4; ++i) {
        GLD16(gp[i],            lp[i]);
        GLD16(gp[i] + jstep[i], lp[i] + 512);
    }
    WAIT_VM0();
    BARRIER();

    for (int t = 0; t < nIter; ++t) {
        const int cbuf = (t & 1) << 14;         // current buffer (halves)
        const int nbuf = 16384 - cbuf;          // next buffer
        half8 bf[4][2], afA[2][2], afB[2][2];

        // ---- phase 0 register loads: all 8 bf + af slice 0 (12 ds_read_b128)
        #pragma unroll
        for (int n = 0; n < 4; ++n) {
            bf[n][0] = *(const half8*)(Bbase + cbuf + n * 1024 + ko0);
            bf[n][1] = *(const half8*)(Bbase + cbuf + n * 1024 + ko1);
        }
        afA[0][0] = *(const half8*)(Abase + cbuf + 0 * 1024 + ko0);
        afA[0][1] = *(const half8*)(Abase + cbuf + 0 * 1024 + ko1);
        afA[1][0] = *(const half8*)(Abase + cbuf + 1 * 1024 + ko0);
        afA[1][1] = *(const half8*)(Abase + cbuf + 1 * 1024 + ko1);

        // ---- issue full DMA of K-tile t+1 into the other buffer.
        // Flight = rest of this K-tile (~2500cy) before the vmcnt(0) drain.
        if (t + 1 < nIter) {
            const int kk = (t + 1) << 6;
            #pragma unroll
            for (int i = 0; i < 4; ++i) {
                GLD16(gp[i] + kk,            lp[i] + nbuf);
                GLD16(gp[i] + kk + jstep[i], lp[i] + nbuf + 512);
            }
        }

        // ---- prefetch af slice 1 (overlaps slice-0 MFMA via counted lgkm)
        afB[0][0] = *(const half8*)(Abase + cbuf + 2 * 1024 + ko0);
        afB[0][1] = *(const half8*)(Abase + cbuf + 2 * 1024 + ko1);
        afB[1][0] = *(const half8*)(Abase + cbuf + 3 * 1024 + ko0);
        afB[1][1] = *(const half8*)(Abase + cbuf + 3 * 1024 + ko1);

        // ---- slice 0 MFMA (rows 0,1)
        __builtin_amdgcn_s_setprio(1);
        #pragma unroll
        for (int ml = 0; ml < 2; ++ml)
            #pragma unroll
            for (int n = 0; n < 4; ++n)
                #pragma unroll
                for (int ks = 0; ks < 2; ++ks)
                    acc[ml][n] = __builtin_amdgcn_mfma_f32_16x16x32_f16(
                        afA[ml][ks], bf[n][ks], acc[ml][n], 0, 0, 0);
        __builtin_amdgcn_s_setprio(0);

        // ---- prefetch af slice 2 into afA; slice 1 MFMA (rows 2,3) from afB
        afA[0][0] = *(const half8*)(Abase + cbuf + 4 * 1024 + ko0);
        afA[0][1] = *(const half8*)(Abase + cbuf + 4 * 1024 + ko1);
        afA[1][0] = *(const half8*)(Abase + cbuf + 5 * 1024 + ko0);
        afA[1][1] = *(const half8*)(Abase + cbuf + 5 * 1024 + ko1);
        __builtin_amdgcn_s_setprio(1);
        #pragma unroll
        for (int ml = 0; ml < 2; ++ml)
            #pragma unroll
            for (int n = 0; n < 4; ++n)
                #pragma unroll
                for (int ks = 0; ks < 2; ++ks)
                    acc[2 + ml][n] = __builtin_amdgcn_mfma_f32_16x16x32_f16(
                        afB[ml][ks], bf[n][ks], acc[2 + ml][n], 0, 0, 0);
        __builtin_amdgcn_s_setprio(0);

        // ---- prefetch af slice 3 into afB; slice 2 MFMA (rows 4,5) from afA
        afB[0][0] = *(const half8*)(Abase + cbuf + 6 * 1024 + ko0);
        afB[0][1] = *(const half8*)(Abase + cbuf + 6 * 1024 + ko1);
        afB[1][0] = *(const half8*)(Abase + cbuf + 7 * 1024 + ko0);
        afB[1][1] = *(const half8*)(Abase + cbuf + 7 * 1024 + ko1);
        __builtin_amdgcn_s_setprio(1);
        #pragma unroll
        for (int ml = 0; ml < 2; ++ml)
            #pragma unroll
            for (int n = 0; n < 4; ++n)
                #pragma unroll
                for (int ks = 0; ks < 2; ++ks)
                    acc[4 + ml][n] = __builtin_amdgcn_mfma_f32_16x16x32_f16(
                        afA[ml][ks], bf[n][ks], acc[4 + ml][n], 0, 0, 0);
        __builtin_amdgcn_s_setprio(0);

        // ---- slice 3 MFMA (rows 6,7) from afB
        __builtin_amdgcn_s_setprio(1);
        #pragma unroll
        for (int ml = 0; ml < 2; ++ml)
            #pragma unroll
            for (int n = 0; n < 4; ++n)
                #pragma unroll
                for (int ks = 0; ks < 2; ++ks)
                    acc[6 + ml][n] = __builtin_amdgcn_mfma_f32_16x16x32_f16(
                        afB[ml][ks], bf[n][ks], acc[6 + ml][n], 0, 0, 0);
        __builtin_amdgcn_s_setprio(0);

        // ---- single per-tile sync: own DMA drained (issued ~1 tile ago),
        // then barrier makes ALL waves' DMA globally visible for the swap.
        WAIT_VM0();
        BARRIER();
    }

    // ---- epilogue: C/D layout col=lane&15, row=(lane>>4)*4+reg (verified)
    const int ecol = lane & 15;
    const int q4   = (lane >> 4) * 4;
    #pragma unroll
    for (int m = 0; m < 8; ++m) {
        #pragma unroll
        for (int n = 0; n < 4; ++n) {
            const int gcol = colBase + wn * 64 + n * 16 + ecol;
            #pragma unroll
            for (int r = 0; r < 4; ++r) {
                const int grow = rowBase + wm * 128 + m * 16 + q4 + r;
                float v = acc[m][n][r];
                if (EPI == 0) {
                    ((half_t*)Cv)[z * bsC + (long long)grow * ldc + gcol] = (half_t)v;
                } else if (EPI == 1) {
                    ((float*)Cv)[(long long)grow * ldc + gcol] = v + bias[gcol];
                } else {
                    // QKV routing: 256-col tile lies inside one of q/k/v's
                    // 1024-col spans (boundaries are multiples of 256)
                    const int mat = colBase >> 10;      // 0=q, 1=k, 2=v
                    const int c   = gcol & 1023;
                    if (mat == 0) {
                        ((half_t*)Cv)[(long long)grow * 1024 + c] = (half_t)(v * 0.03125f);
                    } else if (mat == 1) {
                        ((half_t*)C2)[(long long)grow * 1024 + c] = (half_t)v;
                    } else {
                        // vT[b][c][t], b=grow>>11, t=grow&2047
                        const long long bb = grow >> 11;
                        const long long tt = grow & 2047;
                        ((half_t*)C3)[bb * (1024LL * 2048) + (long long)c * 2048 + tt] = (half_t)v;
                    }
                }
            }
        }
    }
}

// fp32 -> fp16 flat cast, 8 elems/thread
__global__ __launch_bounds__(256)
void cast16(const float* __restrict__ x, half_t* __restrict__ y)
{
    const long long i = ((long long)blockIdx.x * 256 + threadIdx.x) * 8;
    floatx4 a = *(const floatx4*)(x + i);
    floatx4 b = *(const floatx4*)(x + i + 4);
    half8 h;
    #pragma unroll
    for (int j = 0; j < 4; ++j) { h[j] = (half_t)a[j]; h[j + 4] = (half_t)b[j]; }
    *(half8*)(y + i) = h;
}

// 1024x1024 fp32 -> fp16 transposed; grid.z selects which weight
__global__ __launch_bounds__(256)
void cast_transpose4(const float* __restrict__ W0, const float* __restrict__ W1,
                     const float* __restrict__ W2, const float* __restrict__ W3,
                     half_t* __restrict__ WT)
{
    const float* W = (blockIdx.z == 0) ? W0 : (blockIdx.z == 1) ? W1
                   : (blockIdx.z == 2) ? W2 : W3;
    half_t* O = WT + (long long)blockIdx.z * 1024 * 1024;
    __shared__ float t[32][33];
    const int bx = blockIdx.x * 32, by = blockIdx.y * 32;
    const int tx = threadIdx.x, ty = threadIdx.y;
    #pragma unroll
    for (int i = 0; i < 32; i += 8)
        t[ty + i][tx] = W[(long long)(by + ty + i) * 1024 + bx + tx];
    __syncthreads();
    #pragma unroll
    for (int i = 0; i < 32; i += 8)
        O[(long long)(bx + ty + i) * 1024 + by + tx] = (half_t)t[tx][ty + i];
}

// in-place fp16 row softmax over 2048; one 256-thr block per row; half8 I/O
__global__ __launch_bounds__(256)
void softmax_rows(half_t* __restrict__ S)
{
    const long long base = (long long)blockIdx.x * 2048;
    const int t = threadIdx.x;
    half8 h = *(const half8*)(S + base + t * 8);
    float v[8];
    #pragma unroll
    for (int i = 0; i < 8; ++i) v[i] = (float)h[i];
    float m = -3.0e38f;
    #pragma unroll
    for (int i = 0; i < 8; ++i) m = fmaxf(m, v[i]);
    #pragma unroll
    for (int off = 32; off > 0; off >>= 1) m = fmaxf(m, __shfl_down(m, off));
    __shared__ float redm[4], reds[4];
    const int lane = t & 63, wid = t >> 6;
    if (lane == 0) redm[wid] = m;
    __syncthreads();
    const float M = fmaxf(fmaxf(redm[0], redm[1]), fmaxf(redm[2], redm[3]));
    float s = 0.f;
    #pragma unroll
    for (int i = 0; i < 8; ++i) { v[i] = __expf(v[i] - M); s += v[i]; }
    #pragma unroll
    for (int off = 32; off > 0; off >>= 1) s += __shfl_down(s, off);
    if (lane == 0) reds[wid] = s;
    __syncthreads();
    const float inv = 1.0f / (reds[0] + reds[1] + reds[2] + reds[3]);
    #pragma unroll
    for (int i = 0; i < 8; ++i) h[i] = (half_t)(v[i] * inv);
    *(half8*)(S + base + t * 8) = h;
}

extern "C" void kernel_launch(void* const* d_in, const int* in_sizes, int n_in,
                              void* d_out, int out_size, void* d_ws, size_t ws_size,
                              hipStream_t stream)
{
    const float* x  = (const float*)d_in[0];
    const float* Wq = (const float*)d_in[1];
    const float* Wk = (const float*)d_in[2];
    const float* Wv = (const float*)d_in[3];
    const float* Wp = (const float*)d_in[4];
    const float* bp = (const float*)d_in[5];
    float* out = (float*)d_out;

    char* ws = (char*)d_ws;
    const long long MB = 1024LL * 1024LL;
    half_t* WqkvT = (half_t*)(ws + 0 * MB);   // [3072][1024] = WqT|WkT|WvT
    half_t* WpT   = (half_t*)(ws + 6 * MB);
    half_t* q     = (half_t*)(ws + 8 * MB);   // [8][2048][1024]; later ctx
    half_t* k     = (half_t*)(ws + 40 * MB);
    half_t* vT    = (half_t*)(ws + 72 * MB);  // [8][1024][2048]
    half_t* x16   = (half_t*)(ws + 104 * MB); // dead after QKV
    half_t* S     = (half_t*)(ws + 104 * MB); // [8][2048][2048] fp16, overlays x16

    dim3 blk(512);
    cast16<<<8192, dim3(256), 0, stream>>>(x, x16);
    cast_transpose4<<<dim3(32, 32, 4), dim3(32, 8), 0, stream>>>(Wq, Wk, Wv, Wp, WqkvT);

    // fused QKV: [16384,1024] @ [3072,1024]^T, routed epilogue. 768 blocks.
    gemm16<2><<<dim3(12, 64, 1), blk, 0, stream>>>(
        x16, WqkvT, q, k, vT, nullptr, 1024, 1024, 1024, 0, 0, 0, 0);

    // S = q @ k^T (fp16 out), all 8 batches. 512 blocks.
    gemm16<0><<<dim3(8, 8, 8), blk, 0, stream>>>(
        q, k, S, nullptr, nullptr, nullptr, 1024, 1024, 1024, 2048,
        2048LL * 1024, 2048LL * 1024, 2048LL * 2048);

    // P = softmax(S) in place
    softmax_rows<<<8 * 2048, dim3(256), 0, stream>>>(S);

    // ctx = P @ vT^T (fp16), overwrites q. 256 blocks.
    gemm16<0><<<dim3(4, 8, 8), blk, 0, stream>>>(
        S, vT, q, nullptr, nullptr, nullptr, 2048, 2048, 2048, 1024,
        2048LL * 2048, 1024LL * 2048, 2048LL * 1024);

    // out = ctx @ WpT^T + bp (fp32). 256 blocks.
    gemm16<1><<<dim3(4, 64, 1), blk, 0, stream>>>(
        q, WpT, out, nullptr, nullptr, bp, 1024, 1024, 1024, 1024, 0, 0, 0);
}